// Round 8
// baseline (84.463 us; speedup 1.0000x reference)
//
#include <hip/hip_runtime.h>

#define BATCH 131072
#define NS    300
#define H     100
#define BLK   256                 /* 4 waves/block; 3 blocks/CU -> 3 waves/SIMD */
#define EPB   256                 /* elements per block (64 quads x 4) */
#define NQ4   (EPB * NS / 4)      /* 19200 float4 outputs per block; 75*BLK exactly */

#define REP25(M) M(0) M(1) M(2) M(3) M(4) M(5) M(6) M(7) M(8) M(9) M(10) M(11) \
  M(12) M(13) M(14) M(15) M(16) M(17) M(18) M(19) M(20) M(21) M(22) M(23) M(24)

__device__ __forceinline__ float qswap1(float x) {   /* quad_perm [1,0,3,2] */
    return __int_as_float(__builtin_amdgcn_mov_dpp(__float_as_int(x), 0xB1, 0xF, 0xF, true));
}
__device__ __forceinline__ float qswap2(float x) {   /* quad_perm [2,3,0,1] */
    return __int_as_float(__builtin_amdgcn_mov_dpp(__float_as_int(x), 0x4E, 0xF, 0xF, true));
}

__global__ __launch_bounds__(BLK) __attribute__((amdgpu_waves_per_eu(3, 3)))
void lorentz_fused(const float* __restrict__ G,  const float* __restrict__ W1,
                   const float* __restrict__ b1, const float* __restrict__ W2,
                   const float* __restrict__ b2, const float* __restrict__ Ww0,
                   const float* __restrict__ Wwp, const float* __restrict__ Wg,
                   float* __restrict__ out)
{
    /* 51200 B LDS total -> 3 blocks/CU.
       Phase A (MLP): [0,44800) = W2 chunks [j][q][28] as 7 float4; [44800,51200) = heads.
       Phase B (spectrum): sP0/sP1/sP2 (3 x 4096 B) ALIAS the dead W2 region. */
    __shared__ __align__(16) char smem[51200];
    float4* sW2c4  = (float4*)smem;                 /* H*4*7 float4 = 44800 B */
    float4* sHead4 = (float4*)(smem + 44800);       /* H*4 float4   =  6400 B */
    float4* sP04   = (float4*)smem;                 /* EPB float4 = 4096 B (alias) */
    float4* sP14   = (float4*)(smem + 4096);
    float4* sP24   = (float4*)(smem + 8192);

    const int tid = threadIdx.x;

    /* ---- stage W2 (chunked) + heads once per block ---- */
    {
        float* sW2cF = (float*)sW2c4;
        for (int i = tid; i < H * H; i += BLK) {
            int j = i / 100, k = i - j * 100;
            int q = k / 25, kk = k - q * 25;
            sW2cF[(j * 4 + q) * 28 + kk] = W2[i];
        }
        float* sHeadF = (float*)sHead4;
        for (int i = tid; i < H * 4; i += BLK) {
            int j = i >> 2, q = i & 3;
            sHeadF[i * 4 + 0] = Ww0[q * H + j];
            sHeadF[i * 4 + 1] = Wwp[q * H + j];
            sHeadF[i * 4 + 2] = Wg [q * H + j];
            sHeadF[i * 4 + 3] = 0.f;
        }
    }
    __syncthreads();

    const int q  = tid & 3;          /* k-chunk / oscillator owner */
    const int gi = tid >> 2;         /* element group 0..63 (4 elements each) */
    const int e0 = blockIdx.x * EPB + gi * 4;

    /* ---- inputs for 4 elements ---- */
    const float4* gp = (const float4*)(G + (size_t)e0 * 8);
    const float4 ga0 = gp[0], gb0 = gp[1];
    const float4 ga1 = gp[2], gb1 = gp[3];
    const float4 ga2 = gp[4], gb2 = gp[5];
    const float4 ga3 = gp[6], gb3 = gp[7];

    /* ---- layer 1: lane computes h1[q*25 .. q*25+24] for 4 elements.
       W1/b1 read straight from global (3.6 KB, L1-resident). ---- */
#define H1DECL(i) float h1a_##i, h1b_##i, h1c_##i, h1d_##i;
    REP25(H1DECL)
#undef H1DECL
#define L1E(dst, ga, gb)                                                        \
        { float s0 = fmaf(ga.x, ra.x, bb);  float s1 = ga.y * ra.y;             \
          s0 = fmaf(ga.z, ra.z, s0);  s1 = fmaf(ga.w, ra.w, s1);                \
          s0 = fmaf(gb.x, rb.x, s0);  s1 = fmaf(gb.y, rb.y, s1);                \
          s0 = fmaf(gb.z, rb.z, s0);  s1 = fmaf(gb.w, rb.w, s1);                \
          dst = fmaxf(s0 + s1, 0.f); }
#define L1(i) { const float4* r = (const float4*)(W1 + (q * 25 + (i)) * 8);     \
        const float4 ra = r[0], rb = r[1];                                      \
        const float bb = b1[q * 25 + (i)];                                      \
        L1E(h1a_##i, ga0, gb0)  L1E(h1b_##i, ga1, gb1)                          \
        L1E(h1c_##i, ga2, gb2)  L1E(h1d_##i, ga3, gb3) }
    REP25(L1)
#undef L1

    /* ---- layer 2 + heads: per j, 25-fma partial dot x4 elements,
       DPP quad butterfly completes each 100-sum, heads accumulate osc q.
       b2[j] is wave-uniform -> s_load. unroll 1 to cap register pressure. ---- */
    float aw0a = 0.f, awpa = 0.f, agga = 0.f;
    float aw0b = 0.f, awpb = 0.f, aggb = 0.f;
    float aw0c = 0.f, awpc = 0.f, aggc = 0.f;
    float aw0d = 0.f, awpd = 0.f, aggd = 0.f;

#pragma unroll 1
    for (int j = 0; j < H; ++j) {
        const int cb = (j * 4 + q) * 7;
        const float4 c0 = sW2c4[cb + 0], c1 = sW2c4[cb + 1], c2 = sW2c4[cb + 2],
                     c3 = sW2c4[cb + 3], c4 = sW2c4[cb + 4], c5 = sW2c4[cb + 5],
                     c6 = sW2c4[cb + 6];
        const float4 hv  = sHead4[j * 4 + q];
        const float  b2j = b2[j];

        float pa = 0.f, pb = 0.f, pc = 0.f, pd = 0.f;
#define CH1(w, i)                                                               \
        pa = fmaf(h1a_##i, w, pa); pb = fmaf(h1b_##i, w, pb);                   \
        pc = fmaf(h1c_##i, w, pc); pd = fmaf(h1d_##i, w, pd);
#define CH(t, i0, i1, i2, i3)                                                   \
        CH1(c##t.x, i0) CH1(c##t.y, i1) CH1(c##t.z, i2) CH1(c##t.w, i3)
        CH(0, 0, 1, 2, 3)     CH(1, 4, 5, 6, 7)     CH(2, 8, 9, 10, 11)
        CH(3, 12, 13, 14, 15) CH(4, 16, 17, 18, 19) CH(5, 20, 21, 22, 23)
        CH1(c6.x, 24)
#undef CH
#undef CH1
        float sa = pa + qswap1(pa); sa += qswap2(sa);
        float sb = pb + qswap1(pb); sb += qswap2(sb);
        float sc = pc + qswap1(pc); sc += qswap2(sc);
        float sd = pd + qswap1(pd); sd += qswap2(sd);
        const float h2a = fmaxf(sa + b2j, 0.f);
        const float h2b = fmaxf(sb + b2j, 0.f);
        const float h2c = fmaxf(sc + b2j, 0.f);
        const float h2d = fmaxf(sd + b2j, 0.f);

        aw0a = fmaf(h2a, hv.x, aw0a); awpa = fmaf(h2a, hv.y, awpa); agga = fmaf(h2a, hv.z, agga);
        aw0b = fmaf(h2b, hv.x, aw0b); awpb = fmaf(h2b, hv.y, awpb); aggb = fmaf(h2b, hv.z, aggb);
        aw0c = fmaf(h2c, hv.x, aw0c); awpc = fmaf(h2c, hv.y, awpc); aggc = fmaf(h2c, hv.z, aggc);
        aw0d = fmaf(h2d, hv.x, aw0d); awpd = fmaf(h2d, hv.y, awpd); aggd = fmaf(h2d, hv.z, aggd);
    }

    /* ---- all W2/head LDS reads done; repurpose LDS for param tables ---- */
    __syncthreads();
    {
        float* P0 = (float*)sP04; float* P1 = (float*)sP14; float* P2 = (float*)sP24;
#define EMIT(aw, ap, ag, e)                                                     \
        { const float w0 = fmaxf(aw, 0.f), wp = fmaxf(ap, 0.f), gg = fmaxf(ag, 0.f); \
          const int ix = (gi * 4 + (e)) * 4 + q;                                \
          P0[ix] = w0 * w0;  P1[ix] = gg * gg;  P2[ix] = wp * wp * gg; }
        EMIT(aw0a, awpa, agga, 0)
        EMIT(aw0b, awpb, aggb, 1)
        EMIT(aw0c, awpc, aggc, 2)
        EMIT(aw0d, awpd, aggd, 3)
#undef EMIT
    }
    __syncthreads();

    /* ---- spectrum: block's contiguous 256*300-float region, float4 stores.
       75 iterations exactly; e = idx4/75 spans <=2 values per wave -> broadcast. */
    float4* out4 = (float4*)out;
    const size_t base4 = (size_t)blockIdx.x * NQ4;

    for (int it = 0; it < NQ4 / BLK; ++it) {        /* 75 iterations */
        const int idx4 = it * BLK + tid;
        const int e  = idx4 / 75;
        const int k4 = idx4 - e * 75;
        const float4 P0 = sP04[e], P1 = sP14[e], P2 = sP24[e];
        const float kb = (float)(k4 << 2);
        float4 r; float* rp = (float*)&r;
#pragma unroll
        for (int i = 0; i < 4; ++i) {
            const float w   = 0.5f + (kb + (float)i) * 0.015f;
            const float wsq = w * w;
            const float t0 = P0.x - wsq, t1 = P0.y - wsq,
                        t2 = P0.z - wsq, t3 = P0.w - wsq;
            const float d0 = fmaf(t0, t0, wsq * P1.x);
            const float d1 = fmaf(t1, t1, wsq * P1.y);
            const float d2 = fmaf(t2, t2, wsq * P1.z);
            const float d3 = fmaf(t3, t3, wsq * P1.w);
            const float d01 = d0 * d1, d23 = d2 * d3;
            const float D   = d01 * d23;
            const float n01 = fmaf(P2.y, d0, P2.x * d1);
            const float n23 = fmaf(P2.w, d2, P2.z * d3);
            const float N   = fmaf(n01, d23, n23 * d01);
            rp[i] = w * (N * __builtin_amdgcn_rcpf(D));
        }
        out4[base4 + idx4] = r;
    }
}

extern "C" void kernel_launch(void* const* d_in, const int* in_sizes, int n_in,
                              void* d_out, int out_size, void* d_ws, size_t ws_size,
                              hipStream_t stream) {
    const float* G   = (const float*)d_in[0];
    const float* W1  = (const float*)d_in[1];
    const float* b1  = (const float*)d_in[2];
    const float* W2  = (const float*)d_in[3];
    const float* b2  = (const float*)d_in[4];
    const float* Ww0 = (const float*)d_in[5];
    const float* Wwp = (const float*)d_in[6];
    const float* Wg  = (const float*)d_in[7];
    float* out = (float*)d_out;

    dim3 grid(BATCH / EPB);   /* 512 blocks */
    dim3 block(BLK);
    lorentz_fused<<<grid, block, 0, stream>>>(G, W1, b1, W2, b2, Ww0, Wwp, Wg, out);
}